// Round 1
// baseline (19.571 us; speedup 1.0000x reference)
//
#include <hip/hip_runtime.h>

// dag[i,j] = T[i,j] * (i<j ? 1 : (i>j ? 1-T[j,i] : 0)),  T[i,j] = s[i,j]*nr[j]
// s[i,j]  = (ep[i,j] + ge[i,j,0]) > ((1-ep[i,j]) + ge[i,j,1])
// nr[j]   = 1 - ((rp[j] + gr[j,0]) > ((1-rp[j]) + gr[j,1]))

constexpr int TS = 32;          // tile size
constexpr int RPT = TS * TS / 256; // rows-per-thread iterations (=4)

__global__ void nr_kernel(const float* __restrict__ rp,
                          const float* __restrict__ gr,
                          float* __restrict__ nr, int n) {
    int i = blockIdx.x * blockDim.x + threadIdx.x;
    if (i < n) {
        float p  = rp[i];
        float z0 = p + gr[2 * i];
        float z1 = (1.0f - p) + gr[2 * i + 1];
        nr[i] = (z0 > z1) ? 0.0f : 1.0f;
    }
}

__global__ __launch_bounds__(256) void dag_kernel(
    const float* __restrict__ ep,
    const float2* __restrict__ ge,
    const float* __restrict__ nr,
    float* __restrict__ out, int n)
{
    __shared__ float Ash[TS][TS + 1];   // +1 pad -> transposed read is 2-way (free)

    // decode triangular pair index: blocks cover (bi,bj) with bi <= bj
    int p = blockIdx.x;
    int a = (int)((sqrtf(8.0f * (float)p + 1.0f) - 1.0f) * 0.5f);
    while ((a + 1) * (a + 2) / 2 <= p) ++a;   // fix fp rounding
    while (a * (a + 1) / 2 > p) --a;
    const int bi = p - a * (a + 1) / 2;       // bi <= bj
    const int bj = a;

    const int t   = threadIdx.x;
    const int col = t & (TS - 1);
    const int rb  = t >> 5;                   // 0..7
    const int I = bi * TS, J = bj * TS;

    // ---- tile A = T[I.., J..] ----
    const float nrj = nr[J + col];
    float av[RPT];
#pragma unroll
    for (int r = 0; r < RPT; ++r) {
        int row = r * 8 + rb;
        size_t idx = (size_t)(I + row) * n + (size_t)(J + col);
        float pr = ep[idx];
        float2 g = ge[idx];
        float z0 = pr + g.x;
        float z1 = (1.0f - pr) + g.y;
        float T = (z0 > z1) ? nrj : 0.0f;
        av[r] = T;
        Ash[row][col] = T;
    }

    if (bi == bj) {
        __syncthreads();
#pragma unroll
        for (int r = 0; r < RPT; ++r) {
            int row = r * 8 + rb;
            float v;
            if (row == col)      v = 0.0f;
            else if (row < col)  v = av[r];
            else                 v = av[r] * (1.0f - Ash[col][row]);
            out[(size_t)(I + row) * n + (size_t)(J + col)] = v;
        }
    } else {
        // ---- tile B = T[J.., I..] (all global i>j there) ----
        const float nri = nr[I + col];
        float bv[RPT];
#pragma unroll
        for (int r = 0; r < RPT; ++r) {
            int row = r * 8 + rb;
            // upper tile: i = I+row < J+col = j always (bi < bj)
            out[(size_t)(I + row) * n + (size_t)(J + col)] = av[r];
            size_t idx = (size_t)(J + row) * n + (size_t)(I + col);
            float pr = ep[idx];
            float2 g = ge[idx];
            float z0 = pr + g.x;
            float z1 = (1.0f - pr) + g.y;
            bv[r] = (z0 > z1) ? nri : 0.0f;
        }
        __syncthreads();
#pragma unroll
        for (int r = 0; r < RPT; ++r) {
            int row = r * 8 + rb;
            // lower tile: global i' = J+row, j' = I+col, i' > j'
            out[(size_t)(J + row) * n + (size_t)(I + col)] =
                bv[r] * (1.0f - Ash[col][row]);
        }
    }
}

extern "C" void kernel_launch(void* const* d_in, const int* in_sizes, int n_in,
                              void* d_out, int out_size, void* d_ws, size_t ws_size,
                              hipStream_t stream) {
    const float*  rp = (const float*)d_in[0];   // root_probs (N)
    const float*  ep = (const float*)d_in[1];   // edge_probs (N,N)
    const float*  gr = (const float*)d_in[2];   // g_root (N,2)
    const float2* ge = (const float2*)d_in[3];  // g_edge (N,N,2)
    float* out = (float*)d_out;
    float* nr  = (float*)d_ws;                  // N floats
    const int n = in_sizes[0];

    nr_kernel<<<(n + 255) / 256, 256, 0, stream>>>(rp, gr, nr, n);

    const int nb = n / TS;                      // n == 2048, divisible
    const int pairs = nb * (nb + 1) / 2;        // 2080 blocks
    dag_kernel<<<pairs, 256, 0, stream>>>(ep, ge, nr, out, n);
}

// Round 2
// 15.634 us; speedup vs baseline: 1.2518x; 1.2518x over previous
//
#include <hip/hip_runtime.h>

// dag[i,j] = T[i,j] * (i<j ? 1 : (i>j ? 1-T[j,i] : 0)),  T[i,j] = s[i,j]*nr[j]
// s[i,j]  = (ep[i,j] + ge[i,j,0]) > ((1-ep[i,j]) + ge[i,j,1])
// nr[j]   = 1 - ((rp[j] + gr[j,0]) > ((1-rp[j]) + gr[j,1]))

constexpr int TS = 32;

__global__ __launch_bounds__(256) void dag_kernel(
    const float*  __restrict__ rp,
    const float*  __restrict__ ep,
    const float2* __restrict__ gr,
    const float4* __restrict__ ge4,   // g_edge viewed as float4 = 2 gumbel pairs
    float* __restrict__ out, int n)
{
    __shared__ float Ash[TS][TS + 1];
    __shared__ float nrA[TS];
    __shared__ float nrB[TS];

    // triangular pair decode: blocks cover (bi,bj), bi <= bj
    int p = blockIdx.x;
    int a = (int)((sqrtf(8.0f * (float)p + 1.0f) - 1.0f) * 0.5f);
    while ((a + 1) * (a + 2) / 2 <= p) ++a;
    while (a * (a + 1) / 2 > p) --a;
    const int bi = p - a * (a + 1) / 2;
    const int bj = a;
    const int I = bi * TS, J = bj * TS;

    const int t   = threadIdx.x;
    const int row = t >> 3;          // 0..31
    const int c4  = (t & 7) << 2;    // 0,4,...,28

    // fused root indicators for the 64 columns this block touches
    if (t < TS) {
        int j = J + t;
        float pj = rp[j]; float2 g = gr[j];
        nrA[t] = ((pj + g.x) > ((1.0f - pj) + g.y)) ? 0.0f : 1.0f;
    } else if (t < 2 * TS) {
        int j = I + (t - TS);
        float pj = rp[j]; float2 g = gr[j];
        nrB[t - TS] = ((pj + g.x) > ((1.0f - pj) + g.y)) ? 0.0f : 1.0f;
    }
    __syncthreads();

    // ---- tile A = T[I+row][J+c4 .. +3] ----
    const size_t idxA = (size_t)(I + row) * n + (size_t)(J + c4);
    float4 epv = *(const float4*)(ep + idxA);
    float4 q0  = ge4[idxA >> 1];
    float4 q1  = ge4[(idxA >> 1) + 1];
    float av[4];
    av[0] = ((epv.x + q0.x) > ((1.0f - epv.x) + q0.y)) ? nrA[c4 + 0] : 0.0f;
    av[1] = ((epv.y + q0.z) > ((1.0f - epv.y) + q0.w)) ? nrA[c4 + 1] : 0.0f;
    av[2] = ((epv.z + q1.x) > ((1.0f - epv.z) + q1.y)) ? nrA[c4 + 2] : 0.0f;
    av[3] = ((epv.w + q1.z) > ((1.0f - epv.w) + q1.w)) ? nrA[c4 + 3] : 0.0f;
    Ash[row][c4 + 0] = av[0];
    Ash[row][c4 + 1] = av[1];
    Ash[row][c4 + 2] = av[2];
    Ash[row][c4 + 3] = av[3];

    if (bi == bj) {
        __syncthreads();
        float4 v;
        float* vp = &v.x;
#pragma unroll
        for (int c = 0; c < 4; ++c) {
            int col = c4 + c;
            if (row == col)      vp[c] = 0.0f;
            else if (row < col)  vp[c] = av[c];
            else                 vp[c] = av[c] * (1.0f - Ash[col][row]);
        }
        *(float4*)(out + idxA) = v;
    } else {
        // upper tile: i = I+row < J+col = j always
        *(float4*)(out + idxA) = make_float4(av[0], av[1], av[2], av[3]);

        // ---- tile B = T[J+row][I+c4 .. +3] ----
        const size_t idxB = (size_t)(J + row) * n + (size_t)(I + c4);
        float4 epb = *(const float4*)(ep + idxB);
        float4 r0  = ge4[idxB >> 1];
        float4 r1  = ge4[(idxB >> 1) + 1];
        float bv[4];
        bv[0] = ((epb.x + r0.x) > ((1.0f - epb.x) + r0.y)) ? nrB[c4 + 0] : 0.0f;
        bv[1] = ((epb.y + r0.z) > ((1.0f - epb.y) + r0.w)) ? nrB[c4 + 1] : 0.0f;
        bv[2] = ((epb.z + r1.x) > ((1.0f - epb.z) + r1.y)) ? nrB[c4 + 2] : 0.0f;
        bv[3] = ((epb.w + r1.z) > ((1.0f - epb.w) + r1.w)) ? nrB[c4 + 3] : 0.0f;

        __syncthreads();
        // lower tile: global i' = J+row > j' = I+col
        float4 w;
        w.x = bv[0] * (1.0f - Ash[c4 + 0][row]);
        w.y = bv[1] * (1.0f - Ash[c4 + 1][row]);
        w.z = bv[2] * (1.0f - Ash[c4 + 2][row]);
        w.w = bv[3] * (1.0f - Ash[c4 + 3][row]);
        *(float4*)(out + idxB) = w;
    }
}

extern "C" void kernel_launch(void* const* d_in, const int* in_sizes, int n_in,
                              void* d_out, int out_size, void* d_ws, size_t ws_size,
                              hipStream_t stream) {
    const float*  rp = (const float*)d_in[0];   // root_probs (N)
    const float*  ep = (const float*)d_in[1];   // edge_probs (N,N)
    const float2* gr = (const float2*)d_in[2];  // g_root (N,2)
    const float4* ge = (const float4*)d_in[3];  // g_edge (N,N,2) as float4
    float* out = (float*)d_out;
    const int n = in_sizes[0];

    const int nb = n / TS;                      // 2048/32 = 64
    const int pairs = nb * (nb + 1) / 2;        // 2080 blocks
    dag_kernel<<<pairs, 256, 0, stream>>>(rp, ep, gr, ge, out, n);
}